// Round 2
// baseline (1706.994 us; speedup 1.0000x reference)
//
#include <hip/hip_runtime.h>
#include <hip/hip_bf16.h>

#define C 128

// ---------------- zero fill (float4 granularity) ----------------
__global__ __launch_bounds__(256) void zero_kernel(float4* __restrict__ p, long n4) {
    long i = blockIdx.x * 256L + threadIdx.x;
    if (i < n4) p[i] = make_float4(0.f, 0.f, 0.f, 0.f);
}

// ---------------- degree computation ----------------
__global__ __launch_bounds__(256) void deg_kernel(
    const int* __restrict__ ei, int E,
    float* __restrict__ dsrc, float* __restrict__ ddst) {
    int e = blockIdx.x * 256 + threadIdx.x;
    if (e < E) {
        unsafeAtomicAdd(&dsrc[ei[e]], 1.0f);
        unsafeAtomicAdd(&ddst[ei[E + e]], 1.0f);
    }
}

// ---------------- edge weights ----------------
__global__ __launch_bounds__(256) void ew_kernel(
    const int* __restrict__ ei, int E,
    const float* __restrict__ dsrc, const float* __restrict__ ddst,
    float* __restrict__ ew) {
    int e = blockIdx.x * 256 + threadIdx.x;
    if (e < E) {
        float a = dsrc[ei[e]];
        float b = ddst[ei[E + e]];
        float va = a > 0.0f ? rsqrtf(a) : 0.0f;
        float vb = b > 0.0f ? rsqrtf(b) : 0.0f;
        ew[e] = va * vb;
    }
}

// ---------------- scalar coefficients ----------------
// coef[k] = softmax(hop_logits)[k] * exp(-exp(log_scale)*k)
__global__ void coef_kernel(const float* __restrict__ log_scale,
                            const float* __restrict__ hop_logits,
                            float* __restrict__ coef) {
    float s = expf(log_scale[0]);
    float m = hop_logits[0];
    for (int k = 1; k < 4; ++k) m = fmaxf(m, hop_logits[k]);
    float a[4], sum = 0.0f;
    for (int k = 0; k < 4; ++k) { a[k] = expf(hop_logits[k] - m); sum += a[k]; }
    for (int k = 0; k < 4; ++k) coef[k] = (a[k] / sum) * expf(-s * (float)k);
}

// ---------------- acc = coef[0] * x ----------------
__global__ __launch_bounds__(256) void scale_kernel(
    const float4* __restrict__ x, float4* __restrict__ acc,
    const float* __restrict__ coef, long n4) {
    long i = blockIdx.x * 256L + threadIdx.x;
    if (i < n4) {
        float c = coef[0];
        float4 v = x[i];
        v.x *= c; v.y *= c; v.z *= c; v.w *= c;
        acc[i] = v;
    }
}

// ---------------- acc += coef[k] * b ----------------
__global__ __launch_bounds__(256) void axpy_kernel(
    const float4* __restrict__ b, float4* __restrict__ acc,
    const float* __restrict__ coef, int k, long n4) {
    long i = blockIdx.x * 256L + threadIdx.x;
    if (i < n4) {
        float c = coef[k];
        float4 v = b[i];
        float4 o = acc[i];
        o.x += c * v.x; o.y += c * v.y; o.z += c * v.z; o.w += c * v.w;
        acc[i] = o;
    }
}

// ---------------- SpMV: nxt[dst] += ew * cur[src] ----------------
// one 64-lane wave per edge, float2 (8B) per lane
__global__ __launch_bounds__(256) void spmv_kernel(
    const int* __restrict__ ei, int E,
    const float* __restrict__ ew,
    const float* __restrict__ cur, float* __restrict__ nxt) {
    long tid = blockIdx.x * 256L + threadIdx.x;
    int e = (int)(tid >> 6);
    if (e >= E) return;
    int lane = threadIdx.x & 63;
    int s = ei[e];
    int d = ei[E + e];
    float w = ew[e];
    float2 v = ((const float2*)(cur + (long)s * C))[lane];
    float* op = nxt + (long)d * C + lane * 2;
    unsafeAtomicAdd(op,     v.x * w);
    unsafeAtomicAdd(op + 1, v.y * w);
}

// ---------------- in-place matmul: out = out @ W + bias ----------------
// 256 threads, 32 rows/block; W (64KB) + x-tile (16KB) in LDS;
// 4x4 register tile per thread
__global__ __launch_bounds__(256) void matmul_kernel(
    float* __restrict__ out, const float* __restrict__ W,
    const float* __restrict__ bias, int N) {
    __shared__ float Wl[C * C];    // 64 KB
    __shared__ float Xl[32 * C];   // 16 KB
    int t = threadIdx.x;

    // stage W: 128*128 floats = 4096 float4, 16 per thread
    #pragma unroll
    for (int i = 0; i < 16; ++i)
        ((float4*)Wl)[t + i * 256] = ((const float4*)W)[t + i * 256];

    int rowbase = blockIdx.x * 32;
    // stage X tile: 32*128 floats = 1024 float4, 4 per thread
    #pragma unroll
    for (int i = 0; i < 4; ++i) {
        int idx = t + i * 256;      // 0..1023
        int r = idx >> 5;           // 0..31
        int c4 = idx & 31;          // 0..31
        int row = rowbase + r;
        float4 v = make_float4(0.f, 0.f, 0.f, 0.f);
        if (row < N) v = ((const float4*)(out + (long)row * C))[c4];
        ((float4*)(Xl + r * C))[c4] = v;
    }
    __syncthreads();

    int tcol = t & 31;   // col group: cols tcol*4 .. +3
    int trow = t >> 5;   // row group: rows trow*4 .. +3
    float acc[4][4] = {};

    for (int k = 0; k < C; ++k) {
        float4 w4 = ((const float4*)(Wl + k * C))[tcol];
        float xr[4];
        #pragma unroll
        for (int r = 0; r < 4; ++r) xr[r] = Xl[(trow * 4 + r) * C + k];
        #pragma unroll
        for (int r = 0; r < 4; ++r) {
            acc[r][0] += xr[r] * w4.x;
            acc[r][1] += xr[r] * w4.y;
            acc[r][2] += xr[r] * w4.z;
            acc[r][3] += xr[r] * w4.w;
        }
    }

    float4 b4 = ((const float4*)bias)[tcol];
    #pragma unroll
    for (int r = 0; r < 4; ++r) {
        int row = rowbase + trow * 4 + r;
        if (row < N) {
            float4 o;
            o.x = acc[r][0] + b4.x;
            o.y = acc[r][1] + b4.y;
            o.z = acc[r][2] + b4.z;
            o.w = acc[r][3] + b4.w;
            ((float4*)(out + (long)row * C))[tcol] = o;
        }
    }
}

extern "C" void kernel_launch(void* const* d_in, const int* in_sizes, int n_in,
                              void* d_out, int out_size, void* d_ws, size_t ws_size,
                              hipStream_t stream) {
    const float* x          = (const float*)d_in[0];
    const int*   ei         = (const int*)d_in[1];   // int64 in reference -> int32 from harness
    const float* W          = (const float*)d_in[3];
    const float* bias       = (const float*)d_in[4];
    const float* log_scale  = (const float*)d_in[5];
    const float* hop_logits = (const float*)d_in[6];
    float* out = (float*)d_out;

    int N = in_sizes[0] / C;
    int E = in_sizes[1] / 2;

    char* ws = (char*)d_ws;
    size_t nb = (size_t)N * C * sizeof(float);
    float* b0   = (float*)ws;
    float* b1   = (float*)(ws + nb);
    float* dsrc = (float*)(ws + 2 * nb);
    float* ddst = dsrc + N;
    float* ew   = ddst + N;
    float* coef = ew + E;

    int eb = (E + 255) / 256;
    long n4 = (long)N * C / 4;           // d_out float4 count
    int nb4 = (int)((n4 + 255) / 256);
    int spmv_blocks = (int)(((long)E * 64 + 255) / 256);

    // zero degrees (2N floats)
    long degn4 = (2L * N) / 4;
    zero_kernel<<<(int)((degn4 + 255) / 256), 256, 0, stream>>>((float4*)dsrc, degn4);
    deg_kernel<<<eb, 256, 0, stream>>>(ei, E, dsrc, ddst);
    ew_kernel<<<eb, 256, 0, stream>>>(ei, E, dsrc, ddst, ew);
    coef_kernel<<<1, 1, 0, stream>>>(log_scale, hop_logits, coef);

    // acc (in d_out) = c0 * x
    scale_kernel<<<nb4, 256, 0, stream>>>((const float4*)x, (float4*)out, coef, n4);

    // hop 1: x -> b0 ; acc += c1*b0
    zero_kernel<<<nb4, 256, 0, stream>>>((float4*)b0, n4);
    spmv_kernel<<<spmv_blocks, 256, 0, stream>>>(ei, E, ew, x, b0);
    axpy_kernel<<<nb4, 256, 0, stream>>>((const float4*)b0, (float4*)out, coef, 1, n4);

    // hop 2: b0 -> b1 ; acc += c2*b1
    zero_kernel<<<nb4, 256, 0, stream>>>((float4*)b1, n4);
    spmv_kernel<<<spmv_blocks, 256, 0, stream>>>(ei, E, ew, b0, b1);
    axpy_kernel<<<nb4, 256, 0, stream>>>((const float4*)b1, (float4*)out, coef, 2, n4);

    // hop 3: b1 -> b0 ; acc += c3*b0
    zero_kernel<<<nb4, 256, 0, stream>>>((float4*)b0, n4);
    spmv_kernel<<<spmv_blocks, 256, 0, stream>>>(ei, E, ew, b1, b0);
    axpy_kernel<<<nb4, 256, 0, stream>>>((const float4*)b0, (float4*)out, coef, 3, n4);

    // out = acc @ W + bias (in place)
    matmul_kernel<<<(N + 31) / 32, 256, 0, stream>>>(out, W, bias, N);
}

// Round 3
// 398.978 us; speedup vs baseline: 4.2784x; 4.2784x over previous
//
#include <hip/hip_runtime.h>
#include <hip/hip_bf16.h>

#define C 128

// ---------------- zero ints ----------------
__global__ __launch_bounds__(256) void zero_int_kernel(int* __restrict__ p, long n) {
    long i = blockIdx.x * 256L + threadIdx.x;
    if (i < n) p[i] = 0;
}

// ---------------- degree histograms ----------------
__global__ __launch_bounds__(256) void hist_kernel(
    const int* __restrict__ ei, int E,
    int* __restrict__ degs, int* __restrict__ degd) {
    int e = blockIdx.x * 256 + threadIdx.x;
    if (e < E) {
        atomicAdd(&degs[ei[e]], 1);
        atomicAdd(&degd[ei[E + e]], 1);
    }
}

// ---------------- scalar coefficients ----------------
__global__ void coef_kernel(const float* __restrict__ log_scale,
                            const float* __restrict__ hop_logits,
                            float* __restrict__ coef) {
    float s = expf(log_scale[0]);
    float m = hop_logits[0];
    for (int k = 1; k < 4; ++k) m = fmaxf(m, hop_logits[k]);
    float a[4], sum = 0.0f;
    for (int k = 0; k < 4; ++k) { a[k] = expf(hop_logits[k] - m); sum += a[k]; }
    for (int k = 0; k < 4; ++k) coef[k] = (a[k] / sum) * expf(-s * (float)k);
}

// ---------------- dsi = rsqrt(deg_src) ----------------
__global__ __launch_bounds__(256) void dsi_kernel(const int* __restrict__ degs,
                                                  float* __restrict__ dsi, int N) {
    int i = blockIdx.x * 256 + threadIdx.x;
    if (i < N) {
        int d = degs[i];
        dsi[i] = d > 0 ? rsqrtf((float)d) : 0.0f;
    }
}

// ---------------- scan stage 1: per-block exclusive scan ----------------
__global__ __launch_bounds__(256) void scan1_kernel(const int* __restrict__ degd,
                                                    int* __restrict__ rp,
                                                    int* __restrict__ bsum, int N) {
    __shared__ int sm[256];
    int t = threadIdx.x;
    int i = blockIdx.x * 256 + t;
    int v = (i < N) ? degd[i] : 0;
    sm[t] = v;
    __syncthreads();
    for (int off = 1; off < 256; off <<= 1) {
        int add = (t >= off) ? sm[t - off] : 0;
        __syncthreads();
        sm[t] += add;
        __syncthreads();
    }
    if (i < N) rp[i] = sm[t] - v;           // exclusive within block
    if (t == 255) bsum[blockIdx.x] = sm[255];
}

// ---------------- scan stage 2: single-block exclusive scan of block sums ----------------
__global__ __launch_bounds__(512) void scan2_kernel(int* __restrict__ bsum, int nb) {
    __shared__ int sm[512];
    int t = threadIdx.x;
    int v = (t < nb) ? bsum[t] : 0;
    sm[t] = v;
    __syncthreads();
    for (int off = 1; off < 512; off <<= 1) {
        int add = (t >= off) ? sm[t - off] : 0;
        __syncthreads();
        sm[t] += add;
        __syncthreads();
    }
    if (t < nb) bsum[t] = sm[t] - v;        // exclusive
}

// ---------------- scan stage 3: add block offsets; init cursor; rp[N]=E ----------------
__global__ __launch_bounds__(256) void scan3_kernel(int* __restrict__ rp,
                                                    const int* __restrict__ bsum,
                                                    int* __restrict__ cursor, int N, int E) {
    int i = blockIdx.x * 256 + threadIdx.x;
    if (i < N) {
        int v = rp[i] + bsum[i >> 8];
        rp[i] = v;
        cursor[i] = v;
    }
    if (i == 0) rp[N] = E;
}

// ---------------- scatter edges into CSR (by dst) ----------------
__global__ __launch_bounds__(256) void scatter_kernel(const int* __restrict__ ei, int E,
                                                      int* __restrict__ cursor,
                                                      int* __restrict__ csr_src) {
    int e = blockIdx.x * 256 + threadIdx.x;
    if (e < E) {
        int d = ei[E + e];
        int pos = atomicAdd(&cursor[d], 1);
        csr_src[pos] = ei[e];
    }
}

// ---------------- pull-mode hop: one wave per dst node ----------------
// sum = ddi[n] * sum_{e in in(n)} dsi[src_e] * cur[src_e]
// K<3: nxt[n] = sum.  K==1: out[n] = c0*x[n] + c1*sum else out[n] += cK*sum.
template<int K>
__global__ __launch_bounds__(256) void pull_kernel(
    const int* __restrict__ rp, const int* __restrict__ csr_src,
    const float* __restrict__ dsi, const int* __restrict__ degd,
    const float* __restrict__ cur, float* __restrict__ nxt,
    const float* __restrict__ x, float* __restrict__ out,
    const float* __restrict__ coef, int N) {
    int wid = (int)((blockIdx.x * 256L + threadIdx.x) >> 6);
    if (wid >= N) return;
    int lane = threadIdx.x & 63;
    int beg = rp[wid], end = rp[wid + 1];
    float sx = 0.f, sy = 0.f;
    for (int j = beg; j < end; ++j) {
        int src = csr_src[j];
        float w = dsi[src];
        float2 v = ((const float2*)(cur + (long)src * C))[lane];
        sx += w * v.x;
        sy += w * v.y;
    }
    int dd = degd[wid];
    float ddi = dd > 0 ? rsqrtf((float)dd) : 0.0f;
    sx *= ddi; sy *= ddi;
    if (K < 3) ((float2*)(nxt + (long)wid * C))[lane] = make_float2(sx, sy);
    float ck = coef[K];
    float2 o;
    if (K == 1) {
        float c0 = coef[0];
        float2 xv = ((const float2*)(x + (long)wid * C))[lane];
        o.x = c0 * xv.x + ck * sx;
        o.y = c0 * xv.y + ck * sy;
    } else {
        o = ((const float2*)(out + (long)wid * C))[lane];
        o.x += ck * sx;
        o.y += ck * sy;
    }
    ((float2*)(out + (long)wid * C))[lane] = o;
}

// ---------------- in-place matmul: out = out @ W + bias ----------------
__global__ __launch_bounds__(256) void matmul_kernel(
    float* __restrict__ out, const float* __restrict__ W,
    const float* __restrict__ bias, int N) {
    __shared__ float Wl[C * C];    // 64 KB
    __shared__ float Xl[32 * C];   // 16 KB
    int t = threadIdx.x;

    #pragma unroll
    for (int i = 0; i < 16; ++i)
        ((float4*)Wl)[t + i * 256] = ((const float4*)W)[t + i * 256];

    int rowbase = blockIdx.x * 32;
    #pragma unroll
    for (int i = 0; i < 4; ++i) {
        int idx = t + i * 256;
        int r = idx >> 5;
        int c4 = idx & 31;
        int row = rowbase + r;
        float4 v = make_float4(0.f, 0.f, 0.f, 0.f);
        if (row < N) v = ((const float4*)(out + (long)row * C))[c4];
        ((float4*)(Xl + r * C))[c4] = v;
    }
    __syncthreads();

    int tcol = t & 31;
    int trow = t >> 5;
    float acc[4][4] = {};

    for (int k = 0; k < C; ++k) {
        float4 w4 = ((const float4*)(Wl + k * C))[tcol];
        float xr[4];
        #pragma unroll
        for (int r = 0; r < 4; ++r) xr[r] = Xl[(trow * 4 + r) * C + k];
        #pragma unroll
        for (int r = 0; r < 4; ++r) {
            acc[r][0] += xr[r] * w4.x;
            acc[r][1] += xr[r] * w4.y;
            acc[r][2] += xr[r] * w4.z;
            acc[r][3] += xr[r] * w4.w;
        }
    }

    float4 b4 = ((const float4*)bias)[tcol];
    #pragma unroll
    for (int r = 0; r < 4; ++r) {
        int row = rowbase + trow * 4 + r;
        if (row < N) {
            float4 o;
            o.x = acc[r][0] + b4.x;
            o.y = acc[r][1] + b4.y;
            o.z = acc[r][2] + b4.z;
            o.w = acc[r][3] + b4.w;
            ((float4*)(out + (long)row * C))[tcol] = o;
        }
    }
}

extern "C" void kernel_launch(void* const* d_in, const int* in_sizes, int n_in,
                              void* d_out, int out_size, void* d_ws, size_t ws_size,
                              hipStream_t stream) {
    const float* x          = (const float*)d_in[0];
    const int*   ei         = (const int*)d_in[1];   // harness delivers int32
    const float* W          = (const float*)d_in[3];
    const float* bias       = (const float*)d_in[4];
    const float* log_scale  = (const float*)d_in[5];
    const float* hop_logits = (const float*)d_in[6];
    float* out = (float*)d_out;

    int N = in_sizes[0] / C;
    int E = in_sizes[1] / 2;

    char* ws = (char*)d_ws;
    size_t nb = (size_t)N * C * sizeof(float);
    float* b0      = (float*)ws;
    float* b1      = (float*)(ws + nb);
    int*   degs    = (int*)(ws + 2 * nb);
    int*   degd    = degs + N;
    int*   rp      = degd + N;            // N+1
    int*   cursor  = rp + N + 1;
    float* dsi     = (float*)(cursor + N);
    int*   bsum    = (int*)(dsi + N);     // 512
    float* coef    = (float*)(bsum + 512);
    int*   csr_src = (int*)(coef + 4);    // E

    int eb  = (E + 255) / 256;
    int nbk = (N + 255) / 256;            // scan blocks (391 <= 512)
    int pull_blocks = (int)(((long)N * 64 + 255) / 256);

    // CSR build
    zero_int_kernel<<<(int)((2L * N + 255) / 256), 256, 0, stream>>>(degs, 2L * N);
    hist_kernel<<<eb, 256, 0, stream>>>(ei, E, degs, degd);
    coef_kernel<<<1, 1, 0, stream>>>(log_scale, hop_logits, coef);
    dsi_kernel<<<nbk, 256, 0, stream>>>(degs, dsi, N);
    scan1_kernel<<<nbk, 256, 0, stream>>>(degd, rp, bsum, N);
    scan2_kernel<<<1, 512, 0, stream>>>(bsum, nbk);
    scan3_kernel<<<nbk, 256, 0, stream>>>(rp, bsum, cursor, N, E);
    scatter_kernel<<<eb, 256, 0, stream>>>(ei, E, cursor, csr_src);

    // hops (axpy + init fused)
    pull_kernel<1><<<pull_blocks, 256, 0, stream>>>(rp, csr_src, dsi, degd, x,  b0, x, out, coef, N);
    pull_kernel<2><<<pull_blocks, 256, 0, stream>>>(rp, csr_src, dsi, degd, b0, b1, x, out, coef, N);
    pull_kernel<3><<<pull_blocks, 256, 0, stream>>>(rp, csr_src, dsi, degd, b1, b0, x, out, coef, N);

    // out = out @ W + bias (in place)
    matmul_kernel<<<(N + 31) / 32, 256, 0, stream>>>(out, W, bias, N);
}

// Round 4
// 380.139 us; speedup vs baseline: 4.4904x; 1.0496x over previous
//
#include <hip/hip_runtime.h>
#include <hip/hip_bf16.h>

#define C 128

static __device__ __forceinline__ float b2f(unsigned short u) {
    union { unsigned int i; float f; } v;
    v.i = ((unsigned int)u) << 16;
    return v.f;
}
static __device__ __forceinline__ unsigned short f2b(float f) {
    __hip_bfloat16 b = __float2bfloat16(f);   // RNE
    return *reinterpret_cast<unsigned short*>(&b);
}

// ---------------- zero ints ----------------
__global__ __launch_bounds__(256) void zero_int_kernel(int* __restrict__ p, long n) {
    long i = blockIdx.x * 256L + threadIdx.x;
    if (i < n) p[i] = 0;
}

// ---------------- degree histograms ----------------
__global__ __launch_bounds__(256) void hist_kernel(
    const int* __restrict__ ei, int E,
    int* __restrict__ degs, int* __restrict__ degd) {
    int e = blockIdx.x * 256 + threadIdx.x;
    if (e < E) {
        atomicAdd(&degs[ei[e]], 1);
        atomicAdd(&degd[ei[E + e]], 1);
    }
}

// ---------------- scalar coefficients ----------------
__global__ void coef_kernel(const float* __restrict__ log_scale,
                            const float* __restrict__ hop_logits,
                            float* __restrict__ coef) {
    float s = expf(log_scale[0]);
    float m = hop_logits[0];
    for (int k = 1; k < 4; ++k) m = fmaxf(m, hop_logits[k]);
    float a[4], sum = 0.0f;
    for (int k = 0; k < 4; ++k) { a[k] = expf(hop_logits[k] - m); sum += a[k]; }
    for (int k = 0; k < 4; ++k) coef[k] = (a[k] / sum) * expf(-s * (float)k);
}

// ---------------- scan stage 1: per-block inclusive->exclusive scan ----------------
__global__ __launch_bounds__(256) void scan1_kernel(const int* __restrict__ degd,
                                                    int* __restrict__ rp,
                                                    int* __restrict__ bsum, int N) {
    __shared__ int sm[256];
    int t = threadIdx.x;
    int i = blockIdx.x * 256 + t;
    int v = (i < N) ? degd[i] : 0;
    sm[t] = v;
    __syncthreads();
    for (int off = 1; off < 256; off <<= 1) {
        int add = (t >= off) ? sm[t - off] : 0;
        __syncthreads();
        sm[t] += add;
        __syncthreads();
    }
    if (i < N) rp[i] = sm[t] - v;
    if (t == 255) bsum[blockIdx.x] = sm[255];
}

// ---------------- scan stage 2 ----------------
__global__ __launch_bounds__(512) void scan2_kernel(int* __restrict__ bsum, int nb) {
    __shared__ int sm[512];
    int t = threadIdx.x;
    int v = (t < nb) ? bsum[t] : 0;
    sm[t] = v;
    __syncthreads();
    for (int off = 1; off < 512; off <<= 1) {
        int add = (t >= off) ? sm[t - off] : 0;
        __syncthreads();
        sm[t] += add;
        __syncthreads();
    }
    if (t < nb) bsum[t] = sm[t] - v;
}

// ---------------- scan stage 3: offsets + cursor + dsi/ddi; rp[N]=E ----------------
__global__ __launch_bounds__(256) void scan3_kernel(int* __restrict__ rp,
                                                    const int* __restrict__ bsum,
                                                    int* __restrict__ cursor,
                                                    const int* __restrict__ degs,
                                                    const int* __restrict__ degd,
                                                    float* __restrict__ dsi,
                                                    float* __restrict__ ddi,
                                                    int N, int E) {
    int i = blockIdx.x * 256 + threadIdx.x;
    if (i < N) {
        int v = rp[i] + bsum[i >> 8];
        rp[i] = v;
        cursor[i] = v;
        int ds = degs[i];
        dsi[i] = ds > 0 ? rsqrtf((float)ds) : 0.0f;
        int dd = degd[i];
        ddi[i] = dd > 0 ? rsqrtf((float)dd) : 0.0f;
    }
    if (i == 0) rp[N] = E;
}

// ---------------- scatter edges into CSR (by dst) ----------------
__global__ __launch_bounds__(256) void scatter_kernel(const int* __restrict__ ei, int E,
                                                      int* __restrict__ cursor,
                                                      int* __restrict__ csr_src) {
    int e = blockIdx.x * 256 + threadIdx.x;
    if (e < E) {
        int d = ei[E + e];
        int pos = atomicAdd(&cursor[d], 1);
        csr_src[pos] = ei[e];
    }
}

// ---------------- pull-mode hop: one wave per dst node, write bf16 ----------------
// nxt[n] = bf16( ddi[n] * sum_{e in in(n)} dsi[src] * cur[src] )
// SRCF32: cur is f32 (first hop from x), else packed bf16
template<int SRCF32>
__global__ __launch_bounds__(256) void pull_kernel(
    const int* __restrict__ rp, const int* __restrict__ csr_src,
    const float* __restrict__ dsi, const float* __restrict__ ddi,
    const void* __restrict__ cur, unsigned int* __restrict__ nxt, int N) {
    int wid = (int)((blockIdx.x * 256L + threadIdx.x) >> 6);
    if (wid >= N) return;
    int lane = threadIdx.x & 63;
    int beg = rp[wid], end = rp[wid + 1];
    float sx = 0.f, sy = 0.f;
    for (int j = beg; j < end; ++j) {
        int src = csr_src[j];
        float w = dsi[src];
        float vx, vy;
        if (SRCF32) {
            float2 v = ((const float2*)((const float*)cur + (long)src * C))[lane];
            vx = v.x; vy = v.y;
        } else {
            unsigned int u = ((const unsigned int*)cur)[(long)src * (C / 2) + lane];
            vx = b2f((unsigned short)(u & 0xffff));
            vy = b2f((unsigned short)(u >> 16));
        }
        sx += w * vx;
        sy += w * vy;
    }
    float dv = ddi[wid];
    sx *= dv; sy *= dv;
    unsigned int o = (unsigned int)f2b(sx) | ((unsigned int)f2b(sy) << 16);
    nxt[(long)wid * (C / 2) + lane] = o;
}

// ---------------- fused combine + matmul ----------------
// out = (c0*x + c1*h1 + c2*h2 + c3*h3) @ W + bias
__global__ __launch_bounds__(256) void matmul_kernel(
    const float* __restrict__ x,
    const unsigned short* __restrict__ h1,
    const unsigned short* __restrict__ h2,
    const unsigned short* __restrict__ h3,
    const float* __restrict__ coef,
    float* __restrict__ out, const float* __restrict__ W,
    const float* __restrict__ bias, int N) {
    __shared__ float Wl[C * C];    // 64 KB
    __shared__ float Xl[32 * C];   // 16 KB
    int t = threadIdx.x;

    #pragma unroll
    for (int i = 0; i < 16; ++i)
        ((float4*)Wl)[t + i * 256] = ((const float4*)W)[t + i * 256];

    float c0 = coef[0], c1 = coef[1], c2 = coef[2], c3 = coef[3];

    int rowbase = blockIdx.x * 32;
    #pragma unroll
    for (int i = 0; i < 4; ++i) {
        int idx = t + i * 256;     // 0..1023
        int r = idx >> 5;          // 0..31
        int c4 = idx & 31;         // float4 col group
        int row = rowbase + r;
        float4 v = make_float4(0.f, 0.f, 0.f, 0.f);
        if (row < N) {
            long base = (long)row * C + c4 * 4;
            float4 xv = *(const float4*)(x + base);
            ushort4 u1 = *(const ushort4*)(h1 + base);
            ushort4 u2 = *(const ushort4*)(h2 + base);
            ushort4 u3 = *(const ushort4*)(h3 + base);
            v.x = c0 * xv.x + c1 * b2f(u1.x) + c2 * b2f(u2.x) + c3 * b2f(u3.x);
            v.y = c0 * xv.y + c1 * b2f(u1.y) + c2 * b2f(u2.y) + c3 * b2f(u3.y);
            v.z = c0 * xv.z + c1 * b2f(u1.z) + c2 * b2f(u2.z) + c3 * b2f(u3.z);
            v.w = c0 * xv.w + c1 * b2f(u1.w) + c2 * b2f(u2.w) + c3 * b2f(u3.w);
        }
        ((float4*)(Xl + r * C))[c4] = v;
    }
    __syncthreads();

    int tcol = t & 31;
    int trow = t >> 5;
    float acc[4][4] = {};

    for (int k = 0; k < C; ++k) {
        float4 w4 = ((const float4*)(Wl + k * C))[tcol];
        float xr[4];
        #pragma unroll
        for (int r = 0; r < 4; ++r) xr[r] = Xl[(trow * 4 + r) * C + k];
        #pragma unroll
        for (int r = 0; r < 4; ++r) {
            acc[r][0] += xr[r] * w4.x;
            acc[r][1] += xr[r] * w4.y;
            acc[r][2] += xr[r] * w4.z;
            acc[r][3] += xr[r] * w4.w;
        }
    }

    float4 b4 = ((const float4*)bias)[tcol];
    #pragma unroll
    for (int r = 0; r < 4; ++r) {
        int row = rowbase + trow * 4 + r;
        if (row < N) {
            float4 o;
            o.x = acc[r][0] + b4.x;
            o.y = acc[r][1] + b4.y;
            o.z = acc[r][2] + b4.z;
            o.w = acc[r][3] + b4.w;
            ((float4*)(out + (long)row * C))[tcol] = o;
        }
    }
}

extern "C" void kernel_launch(void* const* d_in, const int* in_sizes, int n_in,
                              void* d_out, int out_size, void* d_ws, size_t ws_size,
                              hipStream_t stream) {
    const float* x          = (const float*)d_in[0];
    const int*   ei         = (const int*)d_in[1];   // harness delivers int32
    const float* W          = (const float*)d_in[3];
    const float* bias       = (const float*)d_in[4];
    const float* log_scale  = (const float*)d_in[5];
    const float* hop_logits = (const float*)d_in[6];
    float* out = (float*)d_out;

    int N = in_sizes[0] / C;
    int E = in_sizes[1] / 2;

    char* ws = (char*)d_ws;
    size_t hb = (size_t)N * C * sizeof(unsigned short);  // bf16 hop buffer
    unsigned short* h1 = (unsigned short*)ws;
    unsigned short* h2 = (unsigned short*)(ws + hb);
    unsigned short* h3 = (unsigned short*)(ws + 2 * hb);
    int*   degs    = (int*)(ws + 3 * hb);
    int*   degd    = degs + N;
    int*   rp      = degd + N;            // N+1
    int*   cursor  = rp + N + 1;
    float* dsi     = (float*)(cursor + N);
    float* ddi     = dsi + N;
    int*   bsum    = (int*)(ddi + N);     // 512
    float* coef    = (float*)(bsum + 512);
    int*   csr_src = (int*)(coef + 4);    // E

    int eb  = (E + 255) / 256;
    int nbk = (N + 255) / 256;
    int pull_blocks = (int)(((long)N * 64 + 255) / 256);

    // CSR build
    zero_int_kernel<<<(int)((2L * N + 255) / 256), 256, 0, stream>>>(degs, 2L * N);
    hist_kernel<<<eb, 256, 0, stream>>>(ei, E, degs, degd);
    coef_kernel<<<1, 1, 0, stream>>>(log_scale, hop_logits, coef);
    scan1_kernel<<<nbk, 256, 0, stream>>>(degd, rp, bsum, N);
    scan2_kernel<<<1, 512, 0, stream>>>(bsum, nbk);
    scan3_kernel<<<nbk, 256, 0, stream>>>(rp, bsum, cursor, degs, degd, dsi, ddi, N, E);
    scatter_kernel<<<eb, 256, 0, stream>>>(ei, E, cursor, csr_src);

    // hops: pure gather -> bf16 write
    pull_kernel<1><<<pull_blocks, 256, 0, stream>>>(rp, csr_src, dsi, ddi, x,  (unsigned int*)h1, N);
    pull_kernel<0><<<pull_blocks, 256, 0, stream>>>(rp, csr_src, dsi, ddi, h1, (unsigned int*)h2, N);
    pull_kernel<0><<<pull_blocks, 256, 0, stream>>>(rp, csr_src, dsi, ddi, h2, (unsigned int*)h3, N);

    // out = (c0*x + c1*h1 + c2*h2 + c3*h3) @ W + bias
    matmul_kernel<<<(N + 31) / 32, 256, 0, stream>>>(x, h1, h2, h3, coef, out, W, bias, N);
}

// Round 5
// 279.585 us; speedup vs baseline: 6.1055x; 1.3597x over previous
//
#include <hip/hip_runtime.h>
#include <hip/hip_bf16.h>

#define C 128

static __device__ __forceinline__ float b2f(unsigned short u) {
    union { unsigned int i; float f; } v;
    v.i = ((unsigned int)u) << 16;
    return v.f;
}
static __device__ __forceinline__ unsigned short f2b(float f) {
    __hip_bfloat16 b = __float2bfloat16(f);   // RNE
    return *reinterpret_cast<unsigned short*>(&b);
}

// ---------------- zero ints ----------------
__global__ __launch_bounds__(256) void zero_int_kernel(int* __restrict__ p, long n) {
    long i = blockIdx.x * 256L + threadIdx.x;
    if (i < n) p[i] = 0;
}

// ---------------- degree histograms ----------------
__global__ __launch_bounds__(256) void hist_kernel(
    const int* __restrict__ ei, int E,
    int* __restrict__ degs, int* __restrict__ degd) {
    int e = blockIdx.x * 256 + threadIdx.x;
    if (e < E) {
        atomicAdd(&degs[ei[e]], 1);
        atomicAdd(&degd[ei[E + e]], 1);
    }
}

// ---------------- scalar coefficients ----------------
__global__ void coef_kernel(const float* __restrict__ log_scale,
                            const float* __restrict__ hop_logits,
                            float* __restrict__ coef) {
    float s = expf(log_scale[0]);
    float m = hop_logits[0];
    for (int k = 1; k < 4; ++k) m = fmaxf(m, hop_logits[k]);
    float a[4], sum = 0.0f;
    for (int k = 0; k < 4; ++k) { a[k] = expf(hop_logits[k] - m); sum += a[k]; }
    for (int k = 0; k < 4; ++k) coef[k] = (a[k] / sum) * expf(-s * (float)k);
}

// ---------------- scan stage 1 ----------------
__global__ __launch_bounds__(256) void scan1_kernel(const int* __restrict__ degd,
                                                    int* __restrict__ rp,
                                                    int* __restrict__ bsum, int N) {
    __shared__ int sm[256];
    int t = threadIdx.x;
    int i = blockIdx.x * 256 + t;
    int v = (i < N) ? degd[i] : 0;
    sm[t] = v;
    __syncthreads();
    for (int off = 1; off < 256; off <<= 1) {
        int add = (t >= off) ? sm[t - off] : 0;
        __syncthreads();
        sm[t] += add;
        __syncthreads();
    }
    if (i < N) rp[i] = sm[t] - v;
    if (t == 255) bsum[blockIdx.x] = sm[255];
}

// ---------------- scan stage 2 ----------------
__global__ __launch_bounds__(512) void scan2_kernel(int* __restrict__ bsum, int nb) {
    __shared__ int sm[512];
    int t = threadIdx.x;
    int v = (t < nb) ? bsum[t] : 0;
    sm[t] = v;
    __syncthreads();
    for (int off = 1; off < 512; off <<= 1) {
        int add = (t >= off) ? sm[t - off] : 0;
        __syncthreads();
        sm[t] += add;
        __syncthreads();
    }
    if (t < nb) bsum[t] = sm[t] - v;
}

// ---------------- scan stage 3: offsets + cursor + dsi/ddi; rp[N]=E ----------------
__global__ __launch_bounds__(256) void scan3_kernel(int* __restrict__ rp,
                                                    const int* __restrict__ bsum,
                                                    int* __restrict__ cursor,
                                                    const int* __restrict__ degs,
                                                    const int* __restrict__ degd,
                                                    float* __restrict__ dsi,
                                                    float* __restrict__ ddi,
                                                    int N, int E) {
    int i = blockIdx.x * 256 + threadIdx.x;
    if (i < N) {
        int v = rp[i] + bsum[i >> 8];
        rp[i] = v;
        cursor[i] = v;
        int ds = degs[i];
        dsi[i] = ds > 0 ? rsqrtf((float)ds) : 0.0f;
        int dd = degd[i];
        ddi[i] = dd > 0 ? rsqrtf((float)dd) : 0.0f;
    }
    if (i == 0) rp[N] = E;
}

// ---------------- scatter edges into CSR (by dst), weight folded in ----------------
__global__ __launch_bounds__(256) void scatter_kernel(const int* __restrict__ ei, int E,
                                                      int* __restrict__ cursor,
                                                      const float* __restrict__ dsi,
                                                      int2* __restrict__ csr) {
    int e = blockIdx.x * 256 + threadIdx.x;
    if (e < E) {
        int s = ei[e];
        int d = ei[E + e];
        int pos = atomicAdd(&cursor[d], 1);
        csr[pos] = make_int2(s, __float_as_int(dsi[s]));
    }
}

// ---------------- pull-mode hop: one wave per dst node, 4-way MLP ----------------
// nxt[n] = bf16( ddi[n] * sum_{e in in(n)} w_e * cur[src_e] )
template<int SRCF32>
__global__ __launch_bounds__(256) void pull_kernel(
    const int* __restrict__ rp, const int2* __restrict__ csr,
    const float* __restrict__ ddi,
    const void* __restrict__ cur, unsigned int* __restrict__ nxt, int N) {
    int wid = (int)((blockIdx.x * 256L + threadIdx.x) >> 6);
    if (wid >= N) return;
    int lane = threadIdx.x & 63;
    int beg = __builtin_amdgcn_readfirstlane(rp[wid]);
    int end = __builtin_amdgcn_readfirstlane(rp[wid + 1]);
    const float2* curf = (const float2*)cur;
    const unsigned int* curb = (const unsigned int*)cur;
    float sx = 0.f, sy = 0.f;
    int j = beg;
    for (; j + 4 <= end; j += 4) {
        int2 e0 = csr[j], e1 = csr[j + 1], e2 = csr[j + 2], e3 = csr[j + 3];
        float w0 = __int_as_float(e0.y), w1 = __int_as_float(e1.y);
        float w2 = __int_as_float(e2.y), w3 = __int_as_float(e3.y);
        if (SRCF32) {
            float2 v0 = curf[(long)e0.x * 64 + lane];
            float2 v1 = curf[(long)e1.x * 64 + lane];
            float2 v2 = curf[(long)e2.x * 64 + lane];
            float2 v3 = curf[(long)e3.x * 64 + lane];
            sx += w0 * v0.x + w1 * v1.x + w2 * v2.x + w3 * v3.x;
            sy += w0 * v0.y + w1 * v1.y + w2 * v2.y + w3 * v3.y;
        } else {
            unsigned int u0 = curb[(long)e0.x * 64 + lane];
            unsigned int u1 = curb[(long)e1.x * 64 + lane];
            unsigned int u2 = curb[(long)e2.x * 64 + lane];
            unsigned int u3 = curb[(long)e3.x * 64 + lane];
            sx += w0 * b2f((unsigned short)(u0 & 0xffff)) + w1 * b2f((unsigned short)(u1 & 0xffff))
                + w2 * b2f((unsigned short)(u2 & 0xffff)) + w3 * b2f((unsigned short)(u3 & 0xffff));
            sy += w0 * b2f((unsigned short)(u0 >> 16)) + w1 * b2f((unsigned short)(u1 >> 16))
                + w2 * b2f((unsigned short)(u2 >> 16)) + w3 * b2f((unsigned short)(u3 >> 16));
        }
    }
    for (; j < end; ++j) {
        int2 e = csr[j];
        float w = __int_as_float(e.y);
        if (SRCF32) {
            float2 v = curf[(long)e.x * 64 + lane];
            sx += w * v.x;
            sy += w * v.y;
        } else {
            unsigned int u = curb[(long)e.x * 64 + lane];
            sx += w * b2f((unsigned short)(u & 0xffff));
            sy += w * b2f((unsigned short)(u >> 16));
        }
    }
    float dv = ddi[wid];
    sx *= dv; sy *= dv;
    unsigned int o = (unsigned int)f2b(sx) | ((unsigned int)f2b(sy) << 16);
    nxt[(long)wid * 64 + lane] = o;
}

// ---------------- fused combine + matmul ----------------
// out = (c0*x + c1*h1 + c2*h2 + c3*h3) @ W + bias
__global__ __launch_bounds__(256) void matmul_kernel(
    const float* __restrict__ x,
    const unsigned short* __restrict__ h1,
    const unsigned short* __restrict__ h2,
    const unsigned short* __restrict__ h3,
    const float* __restrict__ coef,
    float* __restrict__ out, const float* __restrict__ W,
    const float* __restrict__ bias, int N) {
    __shared__ float Wl[C * C];    // 64 KB
    __shared__ float Xl[32 * C];   // 16 KB
    int t = threadIdx.x;

    #pragma unroll
    for (int i = 0; i < 16; ++i)
        ((float4*)Wl)[t + i * 256] = ((const float4*)W)[t + i * 256];

    float c0 = coef[0], c1 = coef[1], c2 = coef[2], c3 = coef[3];

    int rowbase = blockIdx.x * 32;
    #pragma unroll
    for (int i = 0; i < 4; ++i) {
        int idx = t + i * 256;
        int r = idx >> 5;
        int c4 = idx & 31;
        int row = rowbase + r;
        float4 v = make_float4(0.f, 0.f, 0.f, 0.f);
        if (row < N) {
            long base = (long)row * C + c4 * 4;
            float4 xv = *(const float4*)(x + base);
            ushort4 u1 = *(const ushort4*)(h1 + base);
            ushort4 u2 = *(const ushort4*)(h2 + base);
            ushort4 u3 = *(const ushort4*)(h3 + base);
            v.x = c0 * xv.x + c1 * b2f(u1.x) + c2 * b2f(u2.x) + c3 * b2f(u3.x);
            v.y = c0 * xv.y + c1 * b2f(u1.y) + c2 * b2f(u2.y) + c3 * b2f(u3.y);
            v.z = c0 * xv.z + c1 * b2f(u1.z) + c2 * b2f(u2.z) + c3 * b2f(u3.z);
            v.w = c0 * xv.w + c1 * b2f(u1.w) + c2 * b2f(u2.w) + c3 * b2f(u3.w);
        }
        ((float4*)(Xl + r * C))[c4] = v;
    }
    __syncthreads();

    int tcol = t & 31;
    int trow = t >> 5;
    float acc[4][4] = {};

    for (int k = 0; k < C; ++k) {
        float4 w4 = ((const float4*)(Wl + k * C))[tcol];
        float xr[4];
        #pragma unroll
        for (int r = 0; r < 4; ++r) xr[r] = Xl[(trow * 4 + r) * C + k];
        #pragma unroll
        for (int r = 0; r < 4; ++r) {
            acc[r][0] += xr[r] * w4.x;
            acc[r][1] += xr[r] * w4.y;
            acc[r][2] += xr[r] * w4.z;
            acc[r][3] += xr[r] * w4.w;
        }
    }

    float4 b4 = ((const float4*)bias)[tcol];
    #pragma unroll
    for (int r = 0; r < 4; ++r) {
        int row = rowbase + trow * 4 + r;
        if (row < N) {
            float4 o;
            o.x = acc[r][0] + b4.x;
            o.y = acc[r][1] + b4.y;
            o.z = acc[r][2] + b4.z;
            o.w = acc[r][3] + b4.w;
            ((float4*)(out + (long)row * C))[tcol] = o;
        }
    }
}

extern "C" void kernel_launch(void* const* d_in, const int* in_sizes, int n_in,
                              void* d_out, int out_size, void* d_ws, size_t ws_size,
                              hipStream_t stream) {
    const float* x          = (const float*)d_in[0];
    const int*   ei         = (const int*)d_in[1];   // harness delivers int32
    const float* W          = (const float*)d_in[3];
    const float* bias       = (const float*)d_in[4];
    const float* log_scale  = (const float*)d_in[5];
    const float* hop_logits = (const float*)d_in[6];
    float* out = (float*)d_out;

    int N = in_sizes[0] / C;
    int E = in_sizes[1] / 2;

    char* ws = (char*)d_ws;
    size_t hb = (size_t)N * C * sizeof(unsigned short);  // 25.6 MB per bf16 hop buffer
    unsigned short* h1 = (unsigned short*)ws;
    unsigned short* h2 = (unsigned short*)(ws + hb);
    unsigned short* h3 = (unsigned short*)(ws + 2 * hb);
    int2*  csr     = (int2*)(ws + 3 * hb);            // E entries (8B-aligned)
    int*   degs    = (int*)(csr + E);
    int*   degd    = degs + N;
    int*   rp      = degd + N;            // N+1
    int*   cursor  = rp + N + 1;
    float* dsi     = (float*)(cursor + N);
    float* ddi     = dsi + N;
    int*   bsum    = (int*)(ddi + N);     // 512
    float* coef    = (float*)(bsum + 512);

    int eb  = (E + 255) / 256;
    int nbk = (N + 255) / 256;
    int pull_blocks = (int)(((long)N * 64 + 255) / 256);

    // CSR build
    zero_int_kernel<<<(int)((2L * N + 255) / 256), 256, 0, stream>>>(degs, 2L * N);
    hist_kernel<<<eb, 256, 0, stream>>>(ei, E, degs, degd);
    coef_kernel<<<1, 1, 0, stream>>>(log_scale, hop_logits, coef);
    scan1_kernel<<<nbk, 256, 0, stream>>>(degd, rp, bsum, N);
    scan2_kernel<<<1, 512, 0, stream>>>(bsum, nbk);
    scan3_kernel<<<nbk, 256, 0, stream>>>(rp, bsum, cursor, degs, degd, dsi, ddi, N, E);
    scatter_kernel<<<eb, 256, 0, stream>>>(ei, E, cursor, dsi, csr);

    // hops: gather with 4-way MLP -> bf16 write
    pull_kernel<1><<<pull_blocks, 256, 0, stream>>>(rp, csr, ddi, x,  (unsigned int*)h1, N);
    pull_kernel<0><<<pull_blocks, 256, 0, stream>>>(rp, csr, ddi, h1, (unsigned int*)h2, N);
    pull_kernel<0><<<pull_blocks, 256, 0, stream>>>(rp, csr, ddi, h2, (unsigned int*)h3, N);

    // out = (c0*x + c1*h1 + c2*h2 + c3*h3) @ W + bias
    matmul_kernel<<<(N + 31) / 32, 256, 0, stream>>>(x, h1, h2, h3, coef, out, W, bias, N);
}

// Round 6
// 253.873 us; speedup vs baseline: 6.7238x; 1.1013x over previous
//
#include <hip/hip_runtime.h>
#include <hip/hip_bf16.h>

#define C 128

typedef short s16x8 __attribute__((ext_vector_type(8)));
typedef float f32x4 __attribute__((ext_vector_type(4)));

static __device__ __forceinline__ float b2f(unsigned short u) {
    union { unsigned int i; float f; } v;
    v.i = ((unsigned int)u) << 16;
    return v.f;
}
static __device__ __forceinline__ unsigned short f2b(float f) {
    __hip_bfloat16 b = __float2bfloat16(f);   // RNE
    return *reinterpret_cast<unsigned short*>(&b);
}

// ---------------- zero ints ----------------
__global__ __launch_bounds__(256) void zero_int_kernel(int* __restrict__ p, long n) {
    long i = blockIdx.x * 256L + threadIdx.x;
    if (i < n) p[i] = 0;
}

// ---------------- degree histograms ----------------
__global__ __launch_bounds__(256) void hist_kernel(
    const int* __restrict__ ei, int E,
    int* __restrict__ degs, int* __restrict__ degd) {
    int e = blockIdx.x * 256 + threadIdx.x;
    if (e < E) {
        atomicAdd(&degs[ei[e]], 1);
        atomicAdd(&degd[ei[E + e]], 1);
    }
}

// ---------------- scalar coefficients ----------------
__global__ void coef_kernel(const float* __restrict__ log_scale,
                            const float* __restrict__ hop_logits,
                            float* __restrict__ coef) {
    float s = expf(log_scale[0]);
    float m = hop_logits[0];
    for (int k = 1; k < 4; ++k) m = fmaxf(m, hop_logits[k]);
    float a[4], sum = 0.0f;
    for (int k = 0; k < 4; ++k) { a[k] = expf(hop_logits[k] - m); sum += a[k]; }
    for (int k = 0; k < 4; ++k) coef[k] = (a[k] / sum) * expf(-s * (float)k);
}

// ---------------- W transpose -> bf16 (one-time, tiny) ----------------
__global__ __launch_bounds__(256) void wt_kernel(const float* __restrict__ W,
                                                 unsigned short* __restrict__ WtB) {
    int tid = blockIdx.x * 256 + threadIdx.x;   // 16384 threads
    int k = tid & 127, c = tid >> 7;
    WtB[c * 128 + k] = f2b(W[k * 128 + c]);
}

// ---------------- scan stage 1 ----------------
__global__ __launch_bounds__(256) void scan1_kernel(const int* __restrict__ degd,
                                                    int* __restrict__ rp,
                                                    int* __restrict__ bsum, int N) {
    __shared__ int sm[256];
    int t = threadIdx.x;
    int i = blockIdx.x * 256 + t;
    int v = (i < N) ? degd[i] : 0;
    sm[t] = v;
    __syncthreads();
    for (int off = 1; off < 256; off <<= 1) {
        int add = (t >= off) ? sm[t - off] : 0;
        __syncthreads();
        sm[t] += add;
        __syncthreads();
    }
    if (i < N) rp[i] = sm[t] - v;
    if (t == 255) bsum[blockIdx.x] = sm[255];
}

// ---------------- scan stage 2 ----------------
__global__ __launch_bounds__(512) void scan2_kernel(int* __restrict__ bsum, int nb) {
    __shared__ int sm[512];
    int t = threadIdx.x;
    int v = (t < nb) ? bsum[t] : 0;
    sm[t] = v;
    __syncthreads();
    for (int off = 1; off < 512; off <<= 1) {
        int add = (t >= off) ? sm[t - off] : 0;
        __syncthreads();
        sm[t] += add;
        __syncthreads();
    }
    if (t < nb) bsum[t] = sm[t] - v;
}

// ---------------- scan stage 3: offsets + cursor + dsi/ddi; rp[N]=E ----------------
__global__ __launch_bounds__(256) void scan3_kernel(int* __restrict__ rp,
                                                    const int* __restrict__ bsum,
                                                    int* __restrict__ cursor,
                                                    const int* __restrict__ degs,
                                                    const int* __restrict__ degd,
                                                    float* __restrict__ dsi,
                                                    float* __restrict__ ddi,
                                                    int N, int E) {
    int i = blockIdx.x * 256 + threadIdx.x;
    if (i < N) {
        int v = rp[i] + bsum[i >> 8];
        rp[i] = v;
        cursor[i] = v;
        int ds = degs[i];
        dsi[i] = ds > 0 ? rsqrtf((float)ds) : 0.0f;
        int dd = degd[i];
        ddi[i] = dd > 0 ? rsqrtf((float)dd) : 0.0f;
    }
    if (i == 0) rp[N] = E;
}

// ---------------- scatter edges into CSR (by dst), weight folded in ----------------
__global__ __launch_bounds__(256) void scatter_kernel(const int* __restrict__ ei, int E,
                                                      int* __restrict__ cursor,
                                                      const float* __restrict__ dsi,
                                                      int2* __restrict__ csr) {
    int e = blockIdx.x * 256 + threadIdx.x;
    if (e < E) {
        int s = ei[e];
        int d = ei[E + e];
        int pos = atomicAdd(&cursor[d], 1);
        csr[pos] = make_int2(s, __float_as_int(dsi[s]));
    }
}

// ---------------- pull-mode hop: one wave per dst node, 4-way MLP ----------------
template<int SRCF32>
__global__ __launch_bounds__(256) void pull_kernel(
    const int* __restrict__ rp, const int2* __restrict__ csr,
    const float* __restrict__ ddi,
    const void* __restrict__ cur, unsigned int* __restrict__ nxt, int N) {
    int wid = (int)((blockIdx.x * 256L + threadIdx.x) >> 6);
    if (wid >= N) return;
    int lane = threadIdx.x & 63;
    int beg = __builtin_amdgcn_readfirstlane(rp[wid]);
    int end = __builtin_amdgcn_readfirstlane(rp[wid + 1]);
    const float2* curf = (const float2*)cur;
    const unsigned int* curb = (const unsigned int*)cur;
    float sx = 0.f, sy = 0.f;
    int j = beg;
    for (; j + 4 <= end; j += 4) {
        int2 e0 = csr[j], e1 = csr[j + 1], e2 = csr[j + 2], e3 = csr[j + 3];
        float w0 = __int_as_float(e0.y), w1 = __int_as_float(e1.y);
        float w2 = __int_as_float(e2.y), w3 = __int_as_float(e3.y);
        if (SRCF32) {
            float2 v0 = curf[(long)e0.x * 64 + lane];
            float2 v1 = curf[(long)e1.x * 64 + lane];
            float2 v2 = curf[(long)e2.x * 64 + lane];
            float2 v3 = curf[(long)e3.x * 64 + lane];
            sx += w0 * v0.x + w1 * v1.x + w2 * v2.x + w3 * v3.x;
            sy += w0 * v0.y + w1 * v1.y + w2 * v2.y + w3 * v3.y;
        } else {
            unsigned int u0 = curb[(long)e0.x * 64 + lane];
            unsigned int u1 = curb[(long)e1.x * 64 + lane];
            unsigned int u2 = curb[(long)e2.x * 64 + lane];
            unsigned int u3 = curb[(long)e3.x * 64 + lane];
            sx += w0 * b2f((unsigned short)(u0 & 0xffff)) + w1 * b2f((unsigned short)(u1 & 0xffff))
                + w2 * b2f((unsigned short)(u2 & 0xffff)) + w3 * b2f((unsigned short)(u3 & 0xffff));
            sy += w0 * b2f((unsigned short)(u0 >> 16)) + w1 * b2f((unsigned short)(u1 >> 16))
                + w2 * b2f((unsigned short)(u2 >> 16)) + w3 * b2f((unsigned short)(u3 >> 16));
        }
    }
    for (; j < end; ++j) {
        int2 e = csr[j];
        float w = __int_as_float(e.y);
        if (SRCF32) {
            float2 v = curf[(long)e.x * 64 + lane];
            sx += w * v.x;
            sy += w * v.y;
        } else {
            unsigned int u = curb[(long)e.x * 64 + lane];
            sx += w * b2f((unsigned short)(u & 0xffff));
            sy += w * b2f((unsigned short)(u >> 16));
        }
    }
    float dv = ddi[wid];
    sx *= dv; sy *= dv;
    unsigned int o = (unsigned int)f2b(sx) | ((unsigned int)f2b(sy) << 16);
    nxt[(long)wid * 64 + lane] = o;
}

// ---------------- MFMA matmul: out = (c0*x + c1*h1 + c2*h2 + c3*h3) @ W + bias ----------------
// 64 rows/block, 4 waves; each wave: 16 rows x 128 cols via 8 col-frags x 4 K-steps.
// A built in registers from global; B (W^T bf16) staged in LDS padded to 136/row.
__global__ __launch_bounds__(256) void mfma_matmul_kernel(
    const float* __restrict__ x,
    const unsigned short* __restrict__ h1,
    const unsigned short* __restrict__ h2,
    const unsigned short* __restrict__ h3,
    const float* __restrict__ coef,
    const unsigned short* __restrict__ WtB,
    const float* __restrict__ bias,
    float* __restrict__ out, int N) {
    __shared__ unsigned short Wl[128 * 136];   // 34816 B, padded rows
    int t = threadIdx.x;

    // stage Wt (bf16): 2048 x 16B chunks, 8 per thread
    #pragma unroll
    for (int i = 0; i < 8; ++i) {
        int ch = t + i * 256;          // 0..2047
        int r = ch >> 4;               // 0..127 (col of W)
        int ko = (ch & 15) * 8;        // k offset
        *(s16x8*)(Wl + r * 136 + ko) = *(const s16x8*)(WtB + r * 128 + ko);
    }
    float c0 = coef[0], c1 = coef[1], c2 = coef[2], c3 = coef[3];
    __syncthreads();

    int wave = t >> 6, lane = t & 63;
    int lsel = lane & 15;              // A row sel / B col sel / D col sel
    int lk   = (lane >> 4) * 8;        // k sub-offset
    int arow = blockIdx.x * 64 + wave * 16 + lsel;
    bool rok = arow < N;
    long rbase = (long)arow * C;

    f32x4 acc[8];
    #pragma unroll
    for (int i = 0; i < 8; ++i) acc[i] = (f32x4){0.f, 0.f, 0.f, 0.f};

    #pragma unroll
    for (int ks = 0; ks < 4; ++ks) {
        int k0 = ks * 32 + lk;
        s16x8 a;
        if (rok) {
            const float* xp = x + rbase + k0;
            float4 xa = *(const float4*)xp;
            float4 xb = *(const float4*)(xp + 4);
            s16x8 u1 = *(const s16x8*)(h1 + rbase + k0);
            s16x8 u2 = *(const s16x8*)(h2 + rbase + k0);
            s16x8 u3 = *(const s16x8*)(h3 + rbase + k0);
            float f0 = c0 * xa.x + c1 * b2f((unsigned short)u1[0]) + c2 * b2f((unsigned short)u2[0]) + c3 * b2f((unsigned short)u3[0]);
            float f1 = c0 * xa.y + c1 * b2f((unsigned short)u1[1]) + c2 * b2f((unsigned short)u2[1]) + c3 * b2f((unsigned short)u3[1]);
            float f2 = c0 * xa.z + c1 * b2f((unsigned short)u1[2]) + c2 * b2f((unsigned short)u2[2]) + c3 * b2f((unsigned short)u3[2]);
            float f3 = c0 * xa.w + c1 * b2f((unsigned short)u1[3]) + c2 * b2f((unsigned short)u2[3]) + c3 * b2f((unsigned short)u3[3]);
            float f4 = c0 * xb.x + c1 * b2f((unsigned short)u1[4]) + c2 * b2f((unsigned short)u2[4]) + c3 * b2f((unsigned short)u3[4]);
            float f5 = c0 * xb.y + c1 * b2f((unsigned short)u1[5]) + c2 * b2f((unsigned short)u2[5]) + c3 * b2f((unsigned short)u3[5]);
            float f6 = c0 * xb.z + c1 * b2f((unsigned short)u1[6]) + c2 * b2f((unsigned short)u2[6]) + c3 * b2f((unsigned short)u3[6]);
            float f7 = c0 * xb.w + c1 * b2f((unsigned short)u1[7]) + c2 * b2f((unsigned short)u2[7]) + c3 * b2f((unsigned short)u3[7]);
            a[0] = (short)f2b(f0); a[1] = (short)f2b(f1);
            a[2] = (short)f2b(f2); a[3] = (short)f2b(f3);
            a[4] = (short)f2b(f4); a[5] = (short)f2b(f5);
            a[6] = (short)f2b(f6); a[7] = (short)f2b(f7);
        } else {
            a = (s16x8)0;
        }
        #pragma unroll
        for (int cf = 0; cf < 8; ++cf) {
            s16x8 b = *(const s16x8*)(Wl + (cf * 16 + lsel) * 136 + k0);
            acc[cf] = __builtin_amdgcn_mfma_f32_16x16x32_bf16(a, b, acc[cf], 0, 0, 0);
        }
    }

    // epilogue: D lane mapping col=lane&15, row=(lane>>4)*4+reg
    int orow0 = blockIdx.x * 64 + wave * 16 + (lane >> 4) * 4;
    #pragma unroll
    for (int cf = 0; cf < 8; ++cf) {
        int ocol = cf * 16 + lsel;
        float bv = bias[ocol];
        #pragma unroll
        for (int r = 0; r < 4; ++r) {
            int orow = orow0 + r;
            if (orow < N) out[(long)orow * C + ocol] = acc[cf][r] + bv;
        }
    }
}

extern "C" void kernel_launch(void* const* d_in, const int* in_sizes, int n_in,
                              void* d_out, int out_size, void* d_ws, size_t ws_size,
                              hipStream_t stream) {
    const float* x          = (const float*)d_in[0];
    const int*   ei         = (const int*)d_in[1];   // harness delivers int32
    const float* W          = (const float*)d_in[3];
    const float* bias       = (const float*)d_in[4];
    const float* log_scale  = (const float*)d_in[5];
    const float* hop_logits = (const float*)d_in[6];
    float* out = (float*)d_out;

    int N = in_sizes[0] / C;
    int E = in_sizes[1] / 2;

    char* ws = (char*)d_ws;
    size_t hb = (size_t)N * C * sizeof(unsigned short);  // 25.6 MB per bf16 hop buffer
    unsigned short* h1 = (unsigned short*)ws;
    unsigned short* h2 = (unsigned short*)(ws + hb);
    unsigned short* h3 = (unsigned short*)(ws + 2 * hb);
    int2*  csr     = (int2*)(ws + 3 * hb);            // E entries
    int*   degs    = (int*)(csr + E);
    int*   degd    = degs + N;
    int*   rp      = degd + N;            // N+1
    int*   cursor  = rp + N + 1;
    float* dsi     = (float*)(cursor + N);
    float* ddi     = dsi + N;
    int*   bsum    = (int*)(ddi + N);     // 512
    float* coef    = (float*)(bsum + 512);
    unsigned short* WtB = (unsigned short*)(coef + 4);  // 128*128 bf16

    int eb  = (E + 255) / 256;
    int nbk = (N + 255) / 256;
    int pull_blocks = (int)(((long)N * 64 + 255) / 256);

    // CSR build + W transpose
    zero_int_kernel<<<(int)((2L * N + 255) / 256), 256, 0, stream>>>(degs, 2L * N);
    hist_kernel<<<eb, 256, 0, stream>>>(ei, E, degs, degd);
    coef_kernel<<<1, 1, 0, stream>>>(log_scale, hop_logits, coef);
    wt_kernel<<<64, 256, 0, stream>>>(W, WtB);
    scan1_kernel<<<nbk, 256, 0, stream>>>(degd, rp, bsum, N);
    scan2_kernel<<<1, 512, 0, stream>>>(bsum, nbk);
    scan3_kernel<<<nbk, 256, 0, stream>>>(rp, bsum, cursor, degs, degd, dsi, ddi, N, E);
    scatter_kernel<<<eb, 256, 0, stream>>>(ei, E, cursor, dsi, csr);

    // hops: gather with 4-way MLP -> bf16 write
    pull_kernel<1><<<pull_blocks, 256, 0, stream>>>(rp, csr, ddi, x,  (unsigned int*)h1, N);
    pull_kernel<0><<<pull_blocks, 256, 0, stream>>>(rp, csr, ddi, h1, (unsigned int*)h2, N);
    pull_kernel<0><<<pull_blocks, 256, 0, stream>>>(rp, csr, ddi, h2, (unsigned int*)h3, N);

    // out = (c0*x + c1*h1 + c2*h2 + c3*h3) @ W + bias  (MFMA)
    mfma_matmul_kernel<<<(N + 63) / 64, 256, 0, stream>>>(x, h1, h2, h3, coef, WtB, bias, out, N);
}

// Round 7
// 248.992 us; speedup vs baseline: 6.8556x; 1.0196x over previous
//
#include <hip/hip_runtime.h>
#include <hip/hip_bf16.h>

#define C 128

typedef short s16x8 __attribute__((ext_vector_type(8)));
typedef float f32x4 __attribute__((ext_vector_type(4)));

static __device__ __forceinline__ float b2f(unsigned short u) {
    union { unsigned int i; float f; } v;
    v.i = ((unsigned int)u) << 16;
    return v.f;
}
static __device__ __forceinline__ unsigned short f2b(float f) {
    __hip_bfloat16 b = __float2bfloat16(f);   // RNE
    return *reinterpret_cast<unsigned short*>(&b);
}

// ---------------- zero ints ----------------
__global__ __launch_bounds__(256) void zero_int_kernel(int* __restrict__ p, long n) {
    long i = blockIdx.x * 256L + threadIdx.x;
    if (i < n) p[i] = 0;
}

// ---------------- degree histograms ----------------
__global__ __launch_bounds__(256) void hist_kernel(
    const int* __restrict__ ei, int E,
    int* __restrict__ degs, int* __restrict__ degd) {
    int e = blockIdx.x * 256 + threadIdx.x;
    if (e < E) {
        atomicAdd(&degs[ei[e]], 1);
        atomicAdd(&degd[ei[E + e]], 1);
    }
}

// ---------------- W transpose -> bf16 + coef (one-time, tiny) ----------------
__global__ __launch_bounds__(256) void wt_kernel(const float* __restrict__ W,
                                                 unsigned short* __restrict__ WtB,
                                                 const float* __restrict__ log_scale,
                                                 const float* __restrict__ hop_logits,
                                                 float* __restrict__ coef) {
    int tid = blockIdx.x * 256 + threadIdx.x;   // 16384 threads
    int k = tid & 127, c = tid >> 7;
    WtB[c * 128 + k] = f2b(W[k * 128 + c]);
    if (tid == 0) {
        float s = expf(log_scale[0]);
        float m = hop_logits[0];
        for (int kk = 1; kk < 4; ++kk) m = fmaxf(m, hop_logits[kk]);
        float a[4], sum = 0.0f;
        for (int kk = 0; kk < 4; ++kk) { a[kk] = expf(hop_logits[kk] - m); sum += a[kk]; }
        for (int kk = 0; kk < 4; ++kk) coef[kk] = (a[kk] / sum) * expf(-s * (float)kk);
    }
}

// ---------------- scan stage 1 ----------------
__global__ __launch_bounds__(256) void scan1_kernel(const int* __restrict__ degd,
                                                    int* __restrict__ rp,
                                                    int* __restrict__ bsum, int N) {
    __shared__ int sm[256];
    int t = threadIdx.x;
    int i = blockIdx.x * 256 + t;
    int v = (i < N) ? degd[i] : 0;
    sm[t] = v;
    __syncthreads();
    for (int off = 1; off < 256; off <<= 1) {
        int add = (t >= off) ? sm[t - off] : 0;
        __syncthreads();
        sm[t] += add;
        __syncthreads();
    }
    if (i < N) rp[i] = sm[t] - v;
    if (t == 255) bsum[blockIdx.x] = sm[255];
}

// ---------------- scan stage 2 ----------------
__global__ __launch_bounds__(512) void scan2_kernel(int* __restrict__ bsum, int nb) {
    __shared__ int sm[512];
    int t = threadIdx.x;
    int v = (t < nb) ? bsum[t] : 0;
    sm[t] = v;
    __syncthreads();
    for (int off = 1; off < 512; off <<= 1) {
        int add = (t >= off) ? sm[t - off] : 0;
        __syncthreads();
        sm[t] += add;
        __syncthreads();
    }
    if (t < nb) bsum[t] = sm[t] - v;
}

// ---------------- scan stage 3: offsets + cursor + dsi/ddi; rp[N]=E ----------------
__global__ __launch_bounds__(256) void scan3_kernel(int* __restrict__ rp,
                                                    const int* __restrict__ bsum,
                                                    int* __restrict__ cursor,
                                                    const int* __restrict__ degs,
                                                    const int* __restrict__ degd,
                                                    float* __restrict__ dsi,
                                                    float* __restrict__ ddi,
                                                    int N, int E) {
    int i = blockIdx.x * 256 + threadIdx.x;
    if (i < N) {
        int v = rp[i] + bsum[i >> 8];
        rp[i] = v;
        cursor[i] = v;
        int ds = degs[i];
        dsi[i] = ds > 0 ? rsqrtf((float)ds) : 0.0f;
        int dd = degd[i];
        ddi[i] = dd > 0 ? rsqrtf((float)dd) : 0.0f;
    }
    if (i == 0) rp[N] = E;
}

// ---------------- scatter edges into CSR (by dst), weight folded in ----------------
__global__ __launch_bounds__(256) void scatter_kernel(const int* __restrict__ ei, int E,
                                                      int* __restrict__ cursor,
                                                      const float* __restrict__ dsi,
                                                      int2* __restrict__ csr) {
    int e = blockIdx.x * 256 + threadIdx.x;
    if (e < E) {
        int s = ei[e];
        int d = ei[E + e];
        int pos = atomicAdd(&cursor[d], 1);
        csr[pos] = make_int2(s, __float_as_int(dsi[s]));
    }
}

// ---------------- pull-mode hop: one wave per dst node ----------------
// Uniform predicated 8-wide gather loop: OOR slots clamp index to beg, weight 0.
template<int SRCF32>
__global__ __launch_bounds__(256) void pull_kernel(
    const int* __restrict__ rp, const int2* __restrict__ csr,
    const float* __restrict__ ddi,
    const void* __restrict__ cur, unsigned int* __restrict__ nxt, int N) {
    int wid = (int)((blockIdx.x * 256L + threadIdx.x) >> 6);
    if (wid >= N) return;
    int lane = threadIdx.x & 63;
    int beg = __builtin_amdgcn_readfirstlane(rp[wid]);
    int end = __builtin_amdgcn_readfirstlane(rp[wid + 1]);
    const float2* curf = (const float2*)cur;
    const unsigned int* curb = (const unsigned int*)cur;
    float sx = 0.f, sy = 0.f;
    if (beg < end) {
        for (int j = beg; j < end; j += 8) {
            int   idx[8];
            float wt[8];
            #pragma unroll
            for (int i = 0; i < 8; ++i) {
                int jj = j + i;
                bool ok = jj < end;
                int2 e = csr[ok ? jj : beg];
                idx[i] = e.x;
                wt[i] = ok ? __int_as_float(e.y) : 0.0f;
            }
            if (SRCF32) {
                float2 v[8];
                #pragma unroll
                for (int i = 0; i < 8; ++i) v[i] = curf[(long)idx[i] * 64 + lane];
                #pragma unroll
                for (int i = 0; i < 8; ++i) { sx += wt[i] * v[i].x; sy += wt[i] * v[i].y; }
            } else {
                unsigned int u[8];
                #pragma unroll
                for (int i = 0; i < 8; ++i) u[i] = curb[(long)idx[i] * 64 + lane];
                #pragma unroll
                for (int i = 0; i < 8; ++i) {
                    sx += wt[i] * b2f((unsigned short)(u[i] & 0xffff));
                    sy += wt[i] * b2f((unsigned short)(u[i] >> 16));
                }
            }
        }
        float dv = ddi[wid];
        sx *= dv; sy *= dv;
    }
    unsigned int o = (unsigned int)f2b(sx) | ((unsigned int)f2b(sy) << 16);
    nxt[(long)wid * 64 + lane] = o;
}

// ---------------- MFMA matmul: out = (c0*x + c1*h1 + c2*h2 + c3*h3) @ W + bias ----------------
__global__ __launch_bounds__(256) void mfma_matmul_kernel(
    const float* __restrict__ x,
    const unsigned short* __restrict__ h1,
    const unsigned short* __restrict__ h2,
    const unsigned short* __restrict__ h3,
    const float* __restrict__ coef,
    const unsigned short* __restrict__ WtB,
    const float* __restrict__ bias,
    float* __restrict__ out, int N) {
    __shared__ unsigned short Wl[128 * 136];   // 34816 B, padded rows
    int t = threadIdx.x;

    #pragma unroll
    for (int i = 0; i < 8; ++i) {
        int ch = t + i * 256;          // 0..2047
        int r = ch >> 4;               // 0..127 (col of W)
        int ko = (ch & 15) * 8;        // k offset
        *(s16x8*)(Wl + r * 136 + ko) = *(const s16x8*)(WtB + r * 128 + ko);
    }
    float c0 = coef[0], c1 = coef[1], c2 = coef[2], c3 = coef[3];
    __syncthreads();

    int wave = t >> 6, lane = t & 63;
    int lsel = lane & 15;
    int lk   = (lane >> 4) * 8;
    int arow = blockIdx.x * 64 + wave * 16 + lsel;
    bool rok = arow < N;
    long rbase = (long)arow * C;

    f32x4 acc[8];
    #pragma unroll
    for (int i = 0; i < 8; ++i) acc[i] = (f32x4){0.f, 0.f, 0.f, 0.f};

    #pragma unroll
    for (int ks = 0; ks < 4; ++ks) {
        int k0 = ks * 32 + lk;
        s16x8 a;
        if (rok) {
            const float* xp = x + rbase + k0;
            float4 xa = *(const float4*)xp;
            float4 xb = *(const float4*)(xp + 4);
            s16x8 u1 = *(const s16x8*)(h1 + rbase + k0);
            s16x8 u2 = *(const s16x8*)(h2 + rbase + k0);
            s16x8 u3 = *(const s16x8*)(h3 + rbase + k0);
            float f0 = c0 * xa.x + c1 * b2f((unsigned short)u1[0]) + c2 * b2f((unsigned short)u2[0]) + c3 * b2f((unsigned short)u3[0]);
            float f1 = c0 * xa.y + c1 * b2f((unsigned short)u1[1]) + c2 * b2f((unsigned short)u2[1]) + c3 * b2f((unsigned short)u3[1]);
            float f2 = c0 * xa.z + c1 * b2f((unsigned short)u1[2]) + c2 * b2f((unsigned short)u2[2]) + c3 * b2f((unsigned short)u3[2]);
            float f3 = c0 * xa.w + c1 * b2f((unsigned short)u1[3]) + c2 * b2f((unsigned short)u2[3]) + c3 * b2f((unsigned short)u3[3]);
            float f4 = c0 * xb.x + c1 * b2f((unsigned short)u1[4]) + c2 * b2f((unsigned short)u2[4]) + c3 * b2f((unsigned short)u3[4]);
            float f5 = c0 * xb.y + c1 * b2f((unsigned short)u1[5]) + c2 * b2f((unsigned short)u2[5]) + c3 * b2f((unsigned short)u3[5]);
            float f6 = c0 * xb.z + c1 * b2f((unsigned short)u1[6]) + c2 * b2f((unsigned short)u2[6]) + c3 * b2f((unsigned short)u3[6]);
            float f7 = c0 * xb.w + c1 * b2f((unsigned short)u1[7]) + c2 * b2f((unsigned short)u2[7]) + c3 * b2f((unsigned short)u3[7]);
            a[0] = (short)f2b(f0); a[1] = (short)f2b(f1);
            a[2] = (short)f2b(f2); a[3] = (short)f2b(f3);
            a[4] = (short)f2b(f4); a[5] = (short)f2b(f5);
            a[6] = (short)f2b(f6); a[7] = (short)f2b(f7);
        } else {
            a = (s16x8)0;
        }
        #pragma unroll
        for (int cf = 0; cf < 8; ++cf) {
            s16x8 b = *(const s16x8*)(Wl + (cf * 16 + lsel) * 136 + k0);
            acc[cf] = __builtin_amdgcn_mfma_f32_16x16x32_bf16(a, b, acc[cf], 0, 0, 0);
        }
    }

    int orow0 = blockIdx.x * 64 + wave * 16 + (lane >> 4) * 4;
    #pragma unroll
    for (int cf = 0; cf < 8; ++cf) {
        int ocol = cf * 16 + lsel;
        float bv = bias[ocol];
        #pragma unroll
        for (int r = 0; r < 4; ++r) {
            int orow = orow0 + r;
            if (orow < N) out[(long)orow * C + ocol] = acc[cf][r] + bv;
        }
    }
}

extern "C" void kernel_launch(void* const* d_in, const int* in_sizes, int n_in,
                              void* d_out, int out_size, void* d_ws, size_t ws_size,
                              hipStream_t stream) {
    const float* x          = (const float*)d_in[0];
    const int*   ei         = (const int*)d_in[1];   // harness delivers int32
    const float* W          = (const float*)d_in[3];
    const float* bias       = (const float*)d_in[4];
    const float* log_scale  = (const float*)d_in[5];
    const float* hop_logits = (const float*)d_in[6];
    float* out = (float*)d_out;

    int N = in_sizes[0] / C;
    int E = in_sizes[1] / 2;

    char* ws = (char*)d_ws;
    size_t hb = (size_t)N * C * sizeof(unsigned short);  // 25.6 MB per bf16 hop buffer
    unsigned short* h1 = (unsigned short*)ws;
    unsigned short* h2 = (unsigned short*)(ws + hb);
    unsigned short* h3 = (unsigned short*)(ws + 2 * hb);
    int2*  csr     = (int2*)(ws + 3 * hb);            // E entries
    int*   degs    = (int*)(csr + E);
    int*   degd    = degs + N;
    int*   rp      = degd + N;            // N+1
    int*   cursor  = rp + N + 1;
    float* dsi     = (float*)(cursor + N);
    float* ddi     = dsi + N;
    int*   bsum    = (int*)(ddi + N);     // 512
    float* coef    = (float*)(bsum + 512);
    unsigned short* WtB = (unsigned short*)(coef + 4);  // 128*128 bf16

    int eb  = (E + 255) / 256;
    int nbk = (N + 255) / 256;
    int pull_blocks = (int)(((long)N * 64 + 255) / 256);

    // CSR build + W transpose + coef
    zero_int_kernel<<<(int)((2L * N + 255) / 256), 256, 0, stream>>>(degs, 2L * N);
    hist_kernel<<<eb, 256, 0, stream>>>(ei, E, degs, degd);
    wt_kernel<<<64, 256, 0, stream>>>(W, WtB, log_scale, hop_logits, coef);
    scan1_kernel<<<nbk, 256, 0, stream>>>(degd, rp, bsum, N);
    scan2_kernel<<<1, 512, 0, stream>>>(bsum, nbk);
    scan3_kernel<<<nbk, 256, 0, stream>>>(rp, bsum, cursor, degs, degd, dsi, ddi, N, E);
    scatter_kernel<<<eb, 256, 0, stream>>>(ei, E, cursor, dsi, csr);

    // hops: predicated 8-wide gather -> bf16 write
    pull_kernel<1><<<pull_blocks, 256, 0, stream>>>(rp, csr, ddi, x,  (unsigned int*)h1, N);
    pull_kernel<0><<<pull_blocks, 256, 0, stream>>>(rp, csr, ddi, h1, (unsigned int*)h2, N);
    pull_kernel<0><<<pull_blocks, 256, 0, stream>>>(rp, csr, ddi, h2, (unsigned int*)h3, N);

    // out = (c0*x + c1*h1 + c2*h2 + c3*h3) @ W + bias  (MFMA)
    mfma_matmul_kernel<<<(N + 63) / 64, 256, 0, stream>>>(x, h1, h2, h3, coef, WtB, bias, out, N);
}